// Round 5
// baseline (638.054 us; speedup 1.0000x reference)
//
#include <hip/hip_runtime.h>
#include <hip/hip_bf16.h>
#include <math.h>

#define K_CB 2
#define DIM 128
#define NEMB 4096
#define HW 1024
#define NPK 32768
#define CCH 256
#define MARGIN 0.15f

typedef __attribute__((ext_vector_type(8))) _Float16 half8;
typedef __attribute__((ext_vector_type(4))) float f32x4;
typedef unsigned long long u64;

// ---------------- zero scratch ----------------
__global__ void k_zero(int* __restrict__ hist, float* __restrict__ diffp,
                       int* __restrict__ cnt, u64* __restrict__ slots,
                       int* __restrict__ bcnt, int* __restrict__ bcur) {
    int t = blockIdx.x * 256 + threadIdx.x;   // 65536
    slots[t] = ~0ull;
    if (t < K_CB * NEMB) { hist[t] = 0; diffp[t] = 0.f; }
    if (t < 128) { bcnt[t] = 0; bcur[t] = 0; }
    if (t < K_CB) cnt[t] = 0;
}

// ---------------- embed -> fp16 [k][j][d] transpose + ||e||^2 fused ----------------
__global__ void k_prep(const float* __restrict__ embed, ushort* __restrict__ ebf,
                       float* __restrict__ enorm) {
    __shared__ ushort tile[DIM][130];
    __shared__ float psum[2][128];
    const int k = blockIdx.x >> 5;
    const int j0 = (blockIdx.x & 31) * 128;
    const int t = threadIdx.x;
    const int jj = t & 127, half = t >> 7;
    const float* ek = embed + (size_t)k * DIM * NEMB;
    float s = 0.f;
    for (int i = 0; i < 64; ++i) {
        int d = i * 2 + half;
        float v = ek[(size_t)d * NEMB + j0 + jj];
        s = fmaf(v, v, s);
        _Float16 h = (_Float16)v;
        tile[d][jj] = *(ushort*)&h;
    }
    psum[half][jj] = s;
    __syncthreads();
    if (t < 128) enorm[k * NEMB + j0 + t] = psum[0][t] + psum[1][t];
    ushort* outk = ebf + ((size_t)k * NEMB + j0) * DIM;
    for (int i = 0; i < 64; ++i) {
        int idx = i * 256 + t;
        int jx = idx >> 7, d = idx & 127;
        outk[(size_t)jx * DIM + d] = tile[d][jx];
    }
}

// ---------------- coarse fp16 MFMA scoring: per-row (best, second, bestChunk64) ----------------
// block (k, 128 rows); 4 waves = 2x2 grid of 64x64 wave tiles. A in registers.
// B double-buffered in LDS (Bs1 reuses A-staging space). 16-wide XOR swizzle both sides.
#define STAGE_B(dst, jt_) do { \
    _Pragma("unroll") \
    for (int it = 0; it < 8; ++it) { \
        int lin = (it * 256 + t) * 16; \
        int row_ = lin >> 8; \
        int col_ = lin & 255; \
        int src_ = row_ * 256 + (col_ ^ ((row_ & 15) << 4)); \
        const char* g_ = (const char*)ebk + (size_t)(jt_) * 32768 + src_; \
        char* l_ = (char*)(dst) + (it * 256 + (t & ~63)) * 16; \
        __builtin_amdgcn_global_load_lds( \
            (const __attribute__((address_space(1))) unsigned int*)g_, \
            (__attribute__((address_space(3))) unsigned int*)l_, 16, 0, 0); \
    } \
} while (0)

__launch_bounds__(256, 2)
__global__ void k_score(const float* __restrict__ x, const ushort* __restrict__ ebf,
                        const float* __restrict__ enorm, int* __restrict__ list,
                        int* __restrict__ cnt, int* __restrict__ chunkbuf,
                        int* __restrict__ bcnt)
{
    __shared__ __align__(16) char smem[65536];
    ushort* As  = (ushort*)smem;            // [0,32K): A fp16 [n][d] swz (prologue only)
    ushort* Bs0 = (ushort*)(smem + 32768);  // [32K,64K)
    ushort* Bs1 = (ushort*)smem;            // reuses As space after prologue

    const int blk = blockIdx.x;
    const int k = blk >> 8;
    const int n0 = (blk & 255) * 128;
    const int b = n0 >> 10;
    const int hw0 = n0 & (HW - 1);
    const int t = threadIdx.x;
    const int lane = t & 63;
    const int w = t >> 6;
    const int wm = w >> 1, wj = w & 1;
    const int l15 = lane & 15, l4 = lane >> 4;

    const ushort* ebk = ebf + (size_t)k * NEMB * DIM;
    const float* enk = enorm + k * NEMB;
    const float* xk = x + ((size_t)(b * CCH + k * DIM)) * HW + hw0;

    // ---- prologue: stage A (transpose fp32->fp16 pairs, swizzled) + stage B tile 0 ----
    {
        const int h = t & 127, half = t >> 7;
        for (int i = 0; i < 32; ++i) {
            int d2 = half * 64 + i * 2;
            float v0 = xk[(size_t)d2 * HW + h];
            float v1 = xk[(size_t)(d2 + 1) * HW + h];
            _Float16 h0 = (_Float16)v0, h1 = (_Float16)v1;
            unsigned int u = ((unsigned int)*(ushort*)&h0) | (((unsigned int)*(ushort*)&h1) << 16);
            int byte = h * 256 + ((d2 * 2) ^ ((h & 15) << 4));
            *(unsigned int*)((char*)As + byte) = u;
        }
    }
    STAGE_B(Bs0, 0);
    __syncthreads();   // drains vmcnt+lgkmcnt: As written, Bs0 landed

    // ---- A-frags to registers: 4 mf x 4 kk ----
    half8 areg[4][4];
#pragma unroll
    for (int mf = 0; mf < 4; ++mf)
#pragma unroll
        for (int kk = 0; kk < 4; ++kk) {
            int row = wm * 64 + mf * 16 + l15;
            int byte = row * 256 + ((kk * 64 + l4 * 16) ^ ((row & 15) << 4));
            areg[mf][kk] = *(const half8*)((const char*)As + byte);
        }
    __syncthreads();   // all A-reads done before Bs1 staging overwrites As

    float best[16], second[16];
    int bchunk[16];
#pragma unroll
    for (int i = 0; i < 16; ++i) { best[i] = 3.4e38f; second[i] = 3.4e38f; bchunk[i] = 0; }

    for (int jt = 0; jt < 32; ++jt) {
        const ushort* Bc = (jt & 1) ? Bs1 : Bs0;
        ushort* Bn = (jt & 1) ? Bs0 : Bs1;
        if (jt < 31) STAGE_B(Bn, jt + 1);

        f32x4 acc[4][4];
#pragma unroll
        for (int mf = 0; mf < 4; ++mf)
#pragma unroll
            for (int jf = 0; jf < 4; ++jf) acc[mf][jf] = (f32x4){0.f, 0.f, 0.f, 0.f};

#pragma unroll
        for (int kk = 0; kk < 4; ++kk) {
            half8 bb[4];
#pragma unroll
            for (int jf = 0; jf < 4; ++jf) {
                int row = wj * 64 + jf * 16 + l15;
                int byte = row * 256 + ((kk * 64 + l4 * 16) ^ ((row & 15) << 4));
                bb[jf] = *(const half8*)((const char*)Bc + byte);
            }
#pragma unroll
            for (int mf = 0; mf < 4; ++mf)
#pragma unroll
                for (int jf = 0; jf < 4; ++jf)
                    acc[mf][jf] = __builtin_amdgcn_mfma_f32_16x16x32_f16(areg[mf][kk], bb[jf], acc[mf][jf], 0, 0, 0);
        }

        // epilogue: per row, 4-score min-tree + (best, second, chunk) triple
        const int cur = jt * 2 + wj;
        float en[4];
#pragma unroll
        for (int jf = 0; jf < 4; ++jf) en[jf] = enk[jt * 128 + wj * 64 + jf * 16 + l15];
#pragma unroll
        for (int mf = 0; mf < 4; ++mf)
#pragma unroll
            for (int r = 0; r < 4; ++r) {
                int ti = mf * 4 + r;
                float s0 = fmaf(-2.f, acc[mf][0][r], en[0]);
                float s1 = fmaf(-2.f, acc[mf][1][r], en[1]);
                float s2 = fmaf(-2.f, acc[mf][2][r], en[2]);
                float s3 = fmaf(-2.f, acc[mf][3][r], en[3]);
                float m = fminf(fminf(s0, s1), fminf(s2, s3));
                float mx = fmaxf(m, best[ti]);
                second[ti] = fminf(second[ti], mx);
                bool lt = m < best[ti];
                bchunk[ti] = lt ? cur : bchunk[ti];
                best[ti] = lt ? m : best[ti];
            }
        __syncthreads();   // drains staging vmcnt; next jt's buffer ready
    }

    // ---- merge across the 16 j-lanes sharing each row ----
#pragma unroll
    for (int off = 1; off < 16; off <<= 1) {
#pragma unroll
        for (int ti = 0; ti < 16; ++ti) {
            float ob = __shfl_xor(best[ti], off);
            float os = __shfl_xor(second[ti], off);
            int oc = __shfl_xor(bchunk[ti], off);
            float ns = fminf(fmaxf(best[ti], ob), fminf(second[ti], os));
            bool take = ob < best[ti];
            bchunk[ti] = take ? oc : bchunk[ti];
            best[ti] = fminf(best[ti], ob);
            second[ti] = ns;
        }
    }

    // ---- merge the two wj waves per row via LDS ----
    __syncthreads();
    float* tb = (float*)smem;          // [128][2]
    float* ts = tb + 256;              // [128][2]
    int*   tc = (int*)(ts + 256);      // [128][2]
    if (l15 == 0) {
#pragma unroll
        for (int ti = 0; ti < 16; ++ti) {
            int mf = ti >> 2, r = ti & 3;
            int row = wm * 64 + mf * 16 + l4 * 4 + r;
            tb[row * 2 + wj] = best[ti];
            ts[row * 2 + wj] = second[ti];
            tc[row * 2 + wj] = bchunk[ti];
        }
    }
    __syncthreads();
    if (t < 128) {
        float b0 = tb[t * 2], b1 = tb[t * 2 + 1];
        float s0 = ts[t * 2], s1 = ts[t * 2 + 1];
        int   c0 = tc[t * 2], c1 = tc[t * 2 + 1];
        float nb = fminf(b0, b1);
        float ns = fminf(fmaxf(b0, b1), fminf(s0, s1));
        int   nc = (b1 < b0) ? c1 : c0;
        int gidx = k * NPK + n0 + t;
        int gch = k * 64 + nc;
        chunkbuf[gidx] = gch;
        atomicAdd(&bcnt[gch], 1);
        if (ns - nb < MARGIN) {
            int p = atomicAdd(&cnt[k], 1);
            list[k * NPK + p] = gidx;
        }
    }
}

// ---------------- exclusive scan of 128 bucket counts ----------------
__global__ void k_scan(const int* __restrict__ bcnt, int* __restrict__ bbase) {
    __shared__ int sc[128];
    int t = threadIdx.x;
    int v = bcnt[t];
    sc[t] = v;
    __syncthreads();
    for (int off = 1; off < 128; off <<= 1) {
        int o = (t >= off) ? sc[t - off] : 0;
        __syncthreads();
        v += o;
        sc[t] = v;
        __syncthreads();
    }
    bbase[t] = v - bcnt[t];
}

// ---------------- scatter rows into chunk buckets ----------------
__global__ void k_scatter(const int* __restrict__ chunkbuf, const int* __restrict__ bbase,
                          int* __restrict__ bcur, int* __restrict__ brows) {
    int g = blockIdx.x * 256 + threadIdx.x;
    int c = chunkbuf[g];
    int p = atomicAdd(&bcur[c], 1);
    brows[bbase[c] + p] = g;
}

// ---------------- exact fp32 scan of each row's best 64-j chunk ----------------
__launch_bounds__(256, 4)
__global__ void k_tile(const float* __restrict__ x, const float* __restrict__ embed,
                       const float* __restrict__ enorm, const int* __restrict__ bcnt,
                       const int* __restrict__ bbase, const int* __restrict__ brows,
                       int* __restrict__ idxw)
{
    __shared__ float el[DIM][64];
    const int c = blockIdx.x >> 3, sub = blockIdx.x & 7;
    const int cn = bcnt[c];
    if (cn == 0) return;
    const int k = c >> 6;
    const int j0 = (c & 63) * 64;
    const int t = threadIdx.x;
    const int lane = t & 63, w = t >> 6;
    const float* ek = embed + (size_t)k * DIM * NEMB;
    for (int ii = t; ii < DIM * 64; ii += 256) {
        int d = ii >> 6, jc = ii & 63;
        el[d][jc] = ek[(size_t)d * NEMB + j0 + jc];
    }
    __syncthreads();
    const float en = enorm[k * NEMB + j0 + lane];
    const int base = bbase[c];
    for (int i = sub * 4 + w; i < cn; i += 32) {
        int row = brows[base + i];
        int n = row & (NPK - 1);
        int bb = n >> 10, hw = n & 1023;
        const float* xr = x + ((size_t)(bb * CCH + k * DIM)) * HW + hw;
        float acc = 0.f;
#pragma unroll 8
        for (int d = 0; d < DIM; ++d)
            acc = fmaf(xr[(size_t)d * HW], el[d][lane], acc);
        float sc = fmaf(-2.f, acc, en);
        unsigned int ub = __float_as_uint(sc);
        unsigned int ou = (sc >= 0.f) ? (ub | 0x80000000u) : ~ub;
        u64 key = ((u64)ou << 32) | (unsigned int)(j0 + lane);
#pragma unroll
        for (int off = 32; off; off >>= 1) {
            u64 o = __shfl_xor(key, off);
            key = o < key ? o : key;
        }
        if (lane == 0) idxw[row] = (int)(key & 0xFFFFFFFFu);
    }
}

// ---------------- exact fp32 rescore of flagged rows (full 4096 j) ----------------
__launch_bounds__(256, 4)
__global__ void k_rescore(const float* __restrict__ x, const float* __restrict__ embed,
                          const float* __restrict__ enorm, const int* __restrict__ list,
                          const int* __restrict__ cnt, u64* __restrict__ slots)
{
    __shared__ float xr[8][128];
    __shared__ u64 part[4][8];
    const int t = threadIdx.x;
    const int lane = t & 63, wv = t >> 6;
    const int c0 = cnt[0], c1 = cnt[1];
    const int items0 = ((c0 + 7) >> 3) * 8;
    const int items1 = ((c1 + 7) >> 3) * 8;
    const int total = items0 + items1;

    for (int item = blockIdx.x; item < total; item += gridDim.x) {
        int k, c, s, ck;
        if (item < items0) { k = 0; c = item >> 3; s = item & 7; ck = c0; }
        else { int it = item - items0; k = 1; c = it >> 3; s = it & 7; ck = c1; }
        const int base = c * 8;
        const int cn = min(8, ck - base);
        __syncthreads();
        for (int ii = t; ii < cn * 128; ii += 256) {
            int ri = ii >> 7, d = ii & 127;
            int gidx = list[k * NPK + base + ri];
            int n = gidx & (NPK - 1);
            int bb = n >> 10, hw = n & 1023;
            xr[ri][d] = x[((size_t)(bb * CCH + k * DIM + d)) * HW + hw];
        }
        __syncthreads();

        u64 key[8];
#pragma unroll
        for (int ri = 0; ri < 8; ++ri) key[ri] = ~0ull;
        const float* ek = embed + (size_t)k * DIM * NEMB;
#pragma unroll
        for (int jj = 0; jj < 2; ++jj) {
            const int j = s * 512 + jj * 256 + t;
            float dot[8];
#pragma unroll
            for (int ri = 0; ri < 8; ++ri) dot[ri] = 0.f;
            for (int d = 0; d < DIM; ++d) {
                float ev = ek[(size_t)d * NEMB + j];
#pragma unroll
                for (int ri = 0; ri < 8; ++ri) dot[ri] = fmaf(xr[ri][d], ev, dot[ri]);
            }
            const float en = enorm[k * NEMB + j];
#pragma unroll
            for (int ri = 0; ri < 8; ++ri) {
                float sc = fmaf(-2.f, dot[ri], en);
                unsigned int bits = __float_as_uint(sc);
                unsigned int u = (sc >= 0.f) ? (bits | 0x80000000u) : ~bits;
                u64 kk = ((u64)u << 32) | (unsigned int)j;
                key[ri] = kk < key[ri] ? kk : key[ri];
            }
        }
#pragma unroll
        for (int off = 32; off; off >>= 1) {
#pragma unroll
            for (int ri = 0; ri < 8; ++ri) {
                u64 o = __shfl_xor(key[ri], off);
                key[ri] = o < key[ri] ? o : key[ri];
            }
        }
        if (lane == 0) {
#pragma unroll
            for (int ri = 0; ri < 8; ++ri) part[wv][ri] = key[ri];
        }
        __syncthreads();
        if (t < 32) {
            int ri = t >> 2, w2 = t & 3;
            u64 kk = part[w2][ri];
            u64 o = __shfl_xor(kk, 1); kk = o < kk ? o : kk;
            o = __shfl_xor(kk, 2);     kk = o < kk ? o : kk;
            if (w2 == 0 && ri < cn)
                atomicMin(&slots[k * NPK + base + ri], kk);
        }
    }
}

// ---------------- write rescored winners back ----------------
__global__ void k_fixup(const int* __restrict__ list, const int* __restrict__ cnt,
                        const u64* __restrict__ slots, int* __restrict__ idxw) {
    int g = blockIdx.x * 256 + threadIdx.x;
#pragma unroll
    for (int k = 0; k < K_CB; ++k)
        if (g < cnt[k])
            idxw[list[k * NPK + g]] = (int)(slots[k * NPK + g] & 0xFFFFFFFFu);
}

// ---------------- gather z_q + diff partials + argf/hist (fused emit) ----------------
__global__ void k_gather(const float* __restrict__ x, const float* __restrict__ embed,
                         const int* __restrict__ idx, float* __restrict__ zq,
                         float* __restrict__ diffp, float* __restrict__ argf,
                         int* __restrict__ hist)
{
    const int blk = blockIdx.x;           // k*4096 + b*128 + d
    const int k = blk >> 12;
    const int b = (blk >> 7) & 31;
    const int d = blk & 127;
    const float* erow = embed + ((size_t)k * DIM + d) * NEMB;
    const int* idxr = idx + k * NPK + b * HW;
    const size_t row = ((size_t)b * CCH + (size_t)k * DIM + d) * HW;
    const float* xr = x + row;
    float* zr = zq + row;
    const int t = threadIdx.x;
    float s = 0.f;
    for (int h = t; h < HW; h += 256) {
        int j = idxr[h];
        float q = erow[j];
        float xv = xr[h];
        float df = q - xv;
        s = fmaf(df, df, s);
        zr[h] = q;
        if (d == 0) {
            argf[k * NPK + b * HW + h] = (float)j;
            atomicAdd(&hist[k * NEMB + j], 1);
        }
    }
    __shared__ float red[256];
    red[t] = s;
    __syncthreads();
    for (int off = 128; off > 0; off >>= 1) {
        if (t < off) red[t] += red[t + off];
        __syncthreads();
    }
    if (t == 0) diffp[blk] = red[0];
}

// ---------------- finalize diffs + perplexity ----------------
__global__ void k_final(const float* __restrict__ diffp, const int* __restrict__ hist,
                        float* __restrict__ diffs, float* __restrict__ ppls)
{
    const int k = blockIdx.x;
    const int t = threadIdx.x;
    __shared__ float red[256];
    float s = 0.f;
    for (int i = t; i < NEMB; i += 256) s += diffp[k * NEMB + i];
    red[t] = s;
    __syncthreads();
    for (int off = 128; off > 0; off >>= 1) {
        if (t < off) red[t] += red[t + off];
        __syncthreads();
    }
    if (t == 0) diffs[k] = red[0] / (float)((size_t)NPK * DIM);
    __syncthreads();
    float s2 = 0.f;
    for (int i = t; i < NEMB; i += 256) {
        float p = (float)hist[k * NEMB + i] * (1.0f / (float)NPK);
        s2 += p * logf(p + 1e-10f);
    }
    red[t] = s2;
    __syncthreads();
    for (int off = 128; off > 0; off >>= 1) {
        if (t < off) red[t] += red[t + off];
        __syncthreads();
    }
    if (t == 0) ppls[k] = expf(-red[0]);
}

extern "C" void kernel_launch(void* const* d_in, const int* in_sizes, int n_in,
                              void* d_out, int out_size, void* d_ws, size_t ws_size,
                              hipStream_t stream) {
    const float* x = (const float*)d_in[0];       // [32,256,32,32]
    const float* embed = (const float*)d_in[1];   // [2,128,4096]
    float* out = (float*)d_out;
    float* zq    = out;                 // 8388608
    float* diffs = out + 8388608;       // 2
    float* argf  = out + 8388610;       // 65536 ([K,B,H,W] as float)
    float* ppls  = out + 8454146;       // 2

    char* W = (char*)d_ws;
    ushort* ebf   = (ushort*)W;                    // 2,097,152 : embedT fp16 [2][4096][128]
    float* enorm  = (float*)(W + 2097152);         // 32768
    int*   idx    = (int*)(W + 2129920);           // 262144
    int*   hist   = (int*)(W + 2392064);           // 32768
    float* diffp  = (float*)(W + 2424832);         // 32768
    int*   list   = (int*)(W + 2457600);           // 262144
    int*   cnt    = (int*)(W + 2719744);           // 64
    u64*   slots  = (u64*)(W + 2719808);           // 524288
    int*   chunkb = (int*)(W + 3244096);           // 262144
    int*   bcnt   = (int*)(W + 3506240);           // 512
    int*   bbase  = (int*)(W + 3506752);           // 512
    int*   bcur   = (int*)(W + 3507264);           // 512
    int*   brows  = (int*)(W + 3507776);           // 262144 -> ends ~3.77 MB

    k_zero   <<<256,  256, 0, stream>>>(hist, diffp, cnt, slots, bcnt, bcur);
    k_prep   <<<64,   256, 0, stream>>>(embed, ebf, enorm);
    k_score  <<<512,  256, 0, stream>>>(x, ebf, enorm, list, cnt, chunkb, bcnt);
    k_scan   <<<1,    128, 0, stream>>>(bcnt, bbase);
    k_scatter<<<256,  256, 0, stream>>>(chunkb, bbase, bcur, brows);
    k_tile   <<<1024, 256, 0, stream>>>(x, embed, enorm, bcnt, bbase, brows, idx);
    k_rescore<<<2048, 256, 0, stream>>>(x, embed, enorm, list, cnt, slots);
    k_fixup  <<<128,  256, 0, stream>>>(list, cnt, slots, idx);
    k_gather <<<8192, 256, 0, stream>>>(x, embed, idx, zq, diffp, argf, hist);
    k_final  <<<2,    256, 0, stream>>>(diffp, hist, diffs, ppls);
}

// Round 6
// 243.815 us; speedup vs baseline: 2.6170x; 2.6170x over previous
//
#include <hip/hip_runtime.h>
#include <hip/hip_bf16.h>
#include <math.h>

#define K_CB 2
#define DIM 128
#define NEMB 4096
#define HW 1024
#define NPK 32768
#define CCH 256
#define MARGIN 0.15f

typedef __attribute__((ext_vector_type(8))) _Float16 half8;
typedef __attribute__((ext_vector_type(4))) float f32x4;
typedef unsigned long long u64;

// ---------------- zero scratch ----------------
__global__ void k_zero(int* __restrict__ hist, int* __restrict__ cnt, u64* __restrict__ slots) {
    int t = blockIdx.x * 256 + threadIdx.x;   // 65536
    slots[t] = ~0ull;
    if (t < K_CB * NEMB) hist[t] = 0;
    if (t < K_CB) cnt[t] = 0;
}

// ---------------- embed -> fp16 [k][j][d] transpose + ||e||^2 fused ----------------
__global__ void k_prep(const float* __restrict__ embed, ushort* __restrict__ ebf,
                       float* __restrict__ enorm) {
    __shared__ ushort tile[DIM][130];
    __shared__ float psum[2][128];
    const int k = blockIdx.x >> 5;
    const int j0 = (blockIdx.x & 31) * 128;
    const int t = threadIdx.x;
    const int jj = t & 127, half = t >> 7;
    const float* ek = embed + (size_t)k * DIM * NEMB;
    float s = 0.f;
    for (int i = 0; i < 64; ++i) {
        int d = i * 2 + half;
        float v = ek[(size_t)d * NEMB + j0 + jj];
        s = fmaf(v, v, s);
        _Float16 h = (_Float16)v;
        tile[d][jj] = *(ushort*)&h;
    }
    psum[half][jj] = s;
    __syncthreads();
    if (t < 128) enorm[k * NEMB + j0 + t] = psum[0][t] + psum[1][t];
    ushort* outk = ebf + ((size_t)k * NEMB + j0) * DIM;
    for (int i = 0; i < 64; ++i) {
        int idx = i * 256 + t;
        int jx = idx >> 7, d = idx & 127;
        outk[(size_t)jx * DIM + d] = tile[d][jx];
    }
}

// ---------------- coarse fp16 MFMA scoring with exact (best, second, bestj) ----------------
// block (k, 128 rows); 4 waves = 2x2 grid of 64x64 wave tiles. A in registers.
// B double-buffered (Bs1 reuses A staging space). 16-wide XOR swizzle both sides.
#define STAGE_B(dst, jt_) do { \
    _Pragma("unroll") \
    for (int it = 0; it < 8; ++it) { \
        int lin = (it * 256 + t) * 16; \
        int row_ = lin >> 8; \
        int col_ = lin & 255; \
        int src_ = row_ * 256 + (col_ ^ ((row_ & 15) << 4)); \
        const char* g_ = (const char*)ebk + (size_t)(jt_) * 32768 + src_; \
        char* l_ = (char*)(dst) + (it * 256 + (t & ~63)) * 16; \
        __builtin_amdgcn_global_load_lds( \
            (const __attribute__((address_space(1))) unsigned int*)g_, \
            (__attribute__((address_space(3))) unsigned int*)l_, 16, 0, 0); \
    } \
} while (0)

__launch_bounds__(256, 2)
__global__ void k_score(const float* __restrict__ x, const ushort* __restrict__ ebf,
                        const float* __restrict__ enorm, int* __restrict__ idxw,
                        float* __restrict__ bestv, float* __restrict__ rnorm,
                        int* __restrict__ list, int* __restrict__ cnt)
{
    __shared__ __align__(16) char smem[65536];
    __shared__ float rn[2][128];
    ushort* As  = (ushort*)smem;            // [0,32K): A fp16 [n][d] swz (prologue only)
    ushort* Bs0 = (ushort*)(smem + 32768);  // [32K,64K)
    ushort* Bs1 = (ushort*)smem;            // reuses As space after prologue

    const int blk = blockIdx.x;
    const int k = blk >> 8;
    const int n0 = (blk & 255) * 128;
    const int b = n0 >> 10;
    const int hw0 = n0 & (HW - 1);
    const int t = threadIdx.x;
    const int lane = t & 63;
    const int w = t >> 6;
    const int wm = w >> 1, wj = w & 1;
    const int l15 = lane & 15, l4 = lane >> 4;

    const ushort* ebk = ebf + (size_t)k * NEMB * DIM;
    const float* enk = enorm + k * NEMB;
    const float* xk = x + ((size_t)(b * CCH + k * DIM)) * HW + hw0;

    // ---- prologue: stage A (fp32->fp16 transpose, swizzled) + row-norms + B tile 0 ----
    {
        const int h = t & 127, half = t >> 7;
        float s = 0.f;
        for (int i = 0; i < 32; ++i) {
            int d2 = half * 64 + i * 2;
            float v0 = xk[(size_t)d2 * HW + h];
            float v1 = xk[(size_t)(d2 + 1) * HW + h];
            s = fmaf(v0, v0, fmaf(v1, v1, s));
            _Float16 h0 = (_Float16)v0, h1 = (_Float16)v1;
            unsigned int u = ((unsigned int)*(ushort*)&h0) | (((unsigned int)*(ushort*)&h1) << 16);
            int byte = h * 256 + ((d2 * 2) ^ ((h & 15) << 4));
            *(unsigned int*)((char*)As + byte) = u;
        }
        rn[half][h] = s;
    }
    STAGE_B(Bs0, 0);
    __syncthreads();   // As written, rn written, Bs0 landed

    if (t < 128) rnorm[k * NPK + n0 + t] = rn[0][t] + rn[1][t];

    // ---- A-frags to registers: 4 mf x 4 kk ----
    half8 areg[4][4];
#pragma unroll
    for (int mf = 0; mf < 4; ++mf)
#pragma unroll
        for (int kk = 0; kk < 4; ++kk) {
            int row = wm * 64 + mf * 16 + l15;
            int byte = row * 256 + ((kk * 64 + l4 * 16) ^ ((row & 15) << 4));
            areg[mf][kk] = *(const half8*)((const char*)As + byte);
        }
    __syncthreads();   // all A-reads done before Bs1 staging overwrites As

    float best[16], second[16];
    int bestj[16];
#pragma unroll
    for (int i = 0; i < 16; ++i) { best[i] = 3.4e38f; second[i] = 3.4e38f; bestj[i] = 0; }

    for (int jt = 0; jt < 32; ++jt) {
        const ushort* Bc = (jt & 1) ? Bs1 : Bs0;
        ushort* Bn = (jt & 1) ? Bs0 : Bs1;
        if (jt < 31) STAGE_B(Bn, jt + 1);

        f32x4 acc[4][4];
#pragma unroll
        for (int mf = 0; mf < 4; ++mf)
#pragma unroll
            for (int jf = 0; jf < 4; ++jf) acc[mf][jf] = (f32x4){0.f, 0.f, 0.f, 0.f};

#pragma unroll
        for (int kk = 0; kk < 4; ++kk) {
            half8 bb[4];
#pragma unroll
            for (int jf = 0; jf < 4; ++jf) {
                int row = wj * 64 + jf * 16 + l15;
                int byte = row * 256 + ((kk * 64 + l4 * 16) ^ ((row & 15) << 4));
                bb[jf] = *(const half8*)((const char*)Bc + byte);
            }
#pragma unroll
            for (int mf = 0; mf < 4; ++mf)
#pragma unroll
                for (int jf = 0; jf < 4; ++jf)
                    acc[mf][jf] = __builtin_amdgcn_mfma_f32_16x16x32_f16(areg[mf][kk], bb[jf], acc[mf][jf], 0, 0, 0);
        }

        // ---- epilogue: exact per-score (best, second, bestj) tracking ----
        float en[4];
#pragma unroll
        for (int jf = 0; jf < 4; ++jf) en[jf] = enk[jt * 128 + wj * 64 + jf * 16 + l15];
#pragma unroll
        for (int jf = 0; jf < 4; ++jf) {
            const int j = jt * 128 + wj * 64 + jf * 16 + l15;
#pragma unroll
            for (int mf = 0; mf < 4; ++mf)
#pragma unroll
                for (int r = 0; r < 4; ++r) {
                    int ti = mf * 4 + r;
                    float s = fmaf(-2.f, acc[mf][jf][r], en[jf]);
                    float mx = fmaxf(s, best[ti]);
                    second[ti] = fminf(second[ti], mx);
                    bool lt = s < best[ti];
                    bestj[ti] = lt ? j : bestj[ti];
                    best[ti] = lt ? s : best[ti];
                }
        }
        __syncthreads();   // next jt's buffer ready
    }

    // ---- merge across the 16 j-lanes sharing each row ----
#pragma unroll
    for (int off = 1; off < 16; off <<= 1) {
#pragma unroll
        for (int ti = 0; ti < 16; ++ti) {
            float ob = __shfl_xor(best[ti], off);
            float os = __shfl_xor(second[ti], off);
            int oj = __shfl_xor(bestj[ti], off);
            float ns = fminf(fmaxf(best[ti], ob), fminf(second[ti], os));
            bool take = (ob < best[ti]) || (ob == best[ti] && oj < bestj[ti]);
            bestj[ti] = take ? oj : bestj[ti];
            best[ti] = fminf(best[ti], ob);
            second[ti] = ns;
        }
    }

    // ---- merge the two wj waves per row via LDS ----
    __syncthreads();
    float* tb = (float*)smem;          // [128][2]
    float* ts = tb + 256;              // [128][2]
    int*   tc = (int*)(ts + 256);      // [128][2]
    if (l15 == 0) {
#pragma unroll
        for (int ti = 0; ti < 16; ++ti) {
            int mf = ti >> 2, r = ti & 3;
            int row = wm * 64 + mf * 16 + l4 * 4 + r;
            tb[row * 2 + wj] = best[ti];
            ts[row * 2 + wj] = second[ti];
            tc[row * 2 + wj] = bestj[ti];
        }
    }
    __syncthreads();
    if (t < 128) {
        float b0 = tb[t * 2], b1 = tb[t * 2 + 1];
        float s0 = ts[t * 2], s1 = ts[t * 2 + 1];
        int   j0 = tc[t * 2], j1 = tc[t * 2 + 1];
        float nb = fminf(b0, b1);
        float ns = fminf(fmaxf(b0, b1), fminf(s0, s1));
        bool take1 = (b1 < b0) || (b1 == b0 && j1 < j0);
        int   nj = take1 ? j1 : j0;
        int gidx = k * NPK + n0 + t;
        idxw[gidx] = nj;
        bestv[gidx] = nb;
        if (ns - nb < MARGIN) {
            int p = atomicAdd(&cnt[k], 1);
            list[k * NPK + p] = gidx;
        }
    }
}

// ---------------- exact fp32 rescore: (8-row chunk) x (512-j slab) items ----------------
__launch_bounds__(256, 4)
__global__ void k_rescore(const float* __restrict__ x, const float* __restrict__ embed,
                          const float* __restrict__ enorm, const int* __restrict__ list,
                          const int* __restrict__ cnt, u64* __restrict__ slots)
{
    __shared__ float xr[8][128];
    __shared__ u64 part[4][8];
    const int t = threadIdx.x;
    const int lane = t & 63, wv = t >> 6;
    const int c0 = cnt[0], c1 = cnt[1];
    const int items0 = ((c0 + 7) >> 3) * 8;
    const int items1 = ((c1 + 7) >> 3) * 8;
    const int total = items0 + items1;

    for (int item = blockIdx.x; item < total; item += gridDim.x) {
        int k, c, s, ck;
        if (item < items0) { k = 0; c = item >> 3; s = item & 7; ck = c0; }
        else { int it = item - items0; k = 1; c = it >> 3; s = it & 7; ck = c1; }
        const int base = c * 8;
        const int cn = min(8, ck - base);
        __syncthreads();
        for (int ii = t; ii < cn * 128; ii += 256) {
            int ri = ii >> 7, d = ii & 127;
            int gidx = list[k * NPK + base + ri];
            int n = gidx & (NPK - 1);
            int bb = n >> 10, hw = n & 1023;
            xr[ri][d] = x[((size_t)(bb * CCH + k * DIM + d)) * HW + hw];
        }
        __syncthreads();

        u64 key[8];
#pragma unroll
        for (int ri = 0; ri < 8; ++ri) key[ri] = ~0ull;
        const float* ek = embed + (size_t)k * DIM * NEMB;
#pragma unroll
        for (int jj = 0; jj < 2; ++jj) {
            const int j = s * 512 + jj * 256 + t;
            float dot[8];
#pragma unroll
            for (int ri = 0; ri < 8; ++ri) dot[ri] = 0.f;
            for (int d = 0; d < DIM; ++d) {
                float ev = ek[(size_t)d * NEMB + j];
#pragma unroll
                for (int ri = 0; ri < 8; ++ri) dot[ri] = fmaf(xr[ri][d], ev, dot[ri]);
            }
            const float en = enorm[k * NEMB + j];
#pragma unroll
            for (int ri = 0; ri < 8; ++ri) {
                float sc = fmaf(-2.f, dot[ri], en);
                unsigned int bits = __float_as_uint(sc);
                unsigned int u = (sc >= 0.f) ? (bits | 0x80000000u) : ~bits;
                u64 kk = ((u64)u << 32) | (unsigned int)j;
                key[ri] = kk < key[ri] ? kk : key[ri];
            }
        }
#pragma unroll
        for (int off = 32; off; off >>= 1) {
#pragma unroll
            for (int ri = 0; ri < 8; ++ri) {
                u64 o = __shfl_xor(key[ri], off);
                key[ri] = o < key[ri] ? o : key[ri];
            }
        }
        if (lane == 0) {
#pragma unroll
            for (int ri = 0; ri < 8; ++ri) part[wv][ri] = key[ri];
        }
        __syncthreads();
        if (t < 32) {
            int ri = t >> 2, w2 = t & 3;
            u64 kk = part[w2][ri];
            u64 o = __shfl_xor(kk, 1); kk = o < kk ? o : kk;
            o = __shfl_xor(kk, 2);     kk = o < kk ? o : kk;
            if (w2 == 0 && ri < cn)
                atomicMin(&slots[k * NPK + base + ri], kk);
        }
    }
}

// ---------------- write rescored winners + exact scores back ----------------
__global__ void k_fixup(const int* __restrict__ list, const int* __restrict__ cnt,
                        const u64* __restrict__ slots, int* __restrict__ idxw,
                        float* __restrict__ bestv) {
    int g = blockIdx.x * 256 + threadIdx.x;
#pragma unroll
    for (int k = 0; k < K_CB; ++k)
        if (g < cnt[k]) {
            u64 sl = slots[k * NPK + g];
            int gidx = list[k * NPK + g];
            idxw[gidx] = (int)(sl & 0xFFFFFFFFu);
            unsigned int u = (unsigned int)(sl >> 32);
            unsigned int bits = (u & 0x80000000u) ? (u & 0x7FFFFFFFu) : ~u;
            bestv[gidx] = __uint_as_float(bits);
        }
}

// ---------------- idx -> argf float + histogram ----------------
__global__ void k_emit(const int* __restrict__ idxw, float* __restrict__ argf, int* __restrict__ hist) {
    int g = blockIdx.x * 256 + threadIdx.x;
    int j = idxw[g];
    argf[g] = (float)j;
    atomicAdd(&hist[(g >> 15) * NEMB + j], 1);
}

// ---------------- gather z_q (no x read; diffs come from scores) ----------------
__global__ void k_gather(const float* __restrict__ embed, const int* __restrict__ idx,
                         float* __restrict__ zq)
{
    const int blk = blockIdx.x;           // k*4096 + b*128 + d
    const int k = blk >> 12;
    const int b = (blk >> 7) & 31;
    const int d = blk & 127;
    const float* erow = embed + ((size_t)k * DIM + d) * NEMB;
    const int* idxr = idx + k * NPK + b * HW;
    float* zr = zq + ((size_t)b * CCH + (size_t)k * DIM + d) * HW;
    const int t = threadIdx.x;
#pragma unroll
    for (int i = 0; i < 4; ++i) {
        int h = i * 256 + t;
        zr[h] = erow[idxr[h]];
    }
}

// ---------------- finalize diffs (rnorm + bestv) + perplexity ----------------
__global__ void k_final(const float* __restrict__ rnorm, const float* __restrict__ bestv,
                        const int* __restrict__ hist, float* __restrict__ diffs,
                        float* __restrict__ ppls)
{
    const int k = blockIdx.x;
    const int t = threadIdx.x;
    __shared__ float red[256];
    float s = 0.f;
    for (int i = t; i < NPK; i += 256)
        s += rnorm[k * NPK + i] + bestv[k * NPK + i];
    red[t] = s;
    __syncthreads();
    for (int off = 128; off > 0; off >>= 1) {
        if (t < off) red[t] += red[t + off];
        __syncthreads();
    }
    if (t == 0) diffs[k] = red[0] / (float)((size_t)NPK * DIM);
    __syncthreads();
    float s2 = 0.f;
    for (int i = t; i < NEMB; i += 256) {
        float p = (float)hist[k * NEMB + i] * (1.0f / (float)NPK);
        s2 += p * logf(p + 1e-10f);
    }
    red[t] = s2;
    __syncthreads();
    for (int off = 128; off > 0; off >>= 1) {
        if (t < off) red[t] += red[t + off];
        __syncthreads();
    }
    if (t == 0) ppls[k] = expf(-red[0]);
}

extern "C" void kernel_launch(void* const* d_in, const int* in_sizes, int n_in,
                              void* d_out, int out_size, void* d_ws, size_t ws_size,
                              hipStream_t stream) {
    const float* x = (const float*)d_in[0];       // [32,256,32,32]
    const float* embed = (const float*)d_in[1];   // [2,128,4096]
    float* out = (float*)d_out;
    float* zq    = out;                 // 8388608
    float* diffs = out + 8388608;       // 2
    float* argf  = out + 8388610;       // 65536 ([K,B,H,W] as float)
    float* ppls  = out + 8454146;       // 2

    char* W = (char*)d_ws;
    ushort* ebf   = (ushort*)W;                    // 2,097,152 : embedT fp16 [2][4096][128]
    float* enorm  = (float*)(W + 2097152);         // 32768
    int*   idx    = (int*)(W + 2129920);           // 262144
    int*   hist   = (int*)(W + 2392064);           // 32768
    float* rnorm  = (float*)(W + 2424832);         // 262144
    float* bestv  = (float*)(W + 2686976);         // 262144
    int*   list   = (int*)(W + 2949120);           // 262144
    int*   cnt    = (int*)(W + 3211264);           // 64
    u64*   slots  = (u64*)(W + 3211328);           // 524288 -> ends ~3.74 MB

    k_zero   <<<256,  256, 0, stream>>>(hist, cnt, slots);
    k_prep   <<<64,   256, 0, stream>>>(embed, ebf, enorm);
    k_score  <<<512,  256, 0, stream>>>(x, ebf, enorm, idx, bestv, rnorm, list, cnt);
    k_rescore<<<2048, 256, 0, stream>>>(x, embed, enorm, list, cnt, slots);
    k_fixup  <<<128,  256, 0, stream>>>(list, cnt, slots, idx, bestv);
    k_emit   <<<256,  256, 0, stream>>>(idx, argf, hist);
    k_gather <<<8192, 256, 0, stream>>>(embed, idx, zq);
    k_final  <<<2,    256, 0, stream>>>(rnorm, bestv, hist, diffs, ppls);
}

// Round 7
// 236.120 us; speedup vs baseline: 2.7022x; 1.0326x over previous
//
#include <hip/hip_runtime.h>
#include <hip/hip_bf16.h>
#include <math.h>

#define K_CB 2
#define DIM 128
#define NEMB 4096
#define HW 1024
#define NPK 32768
#define CCH 256
#define MARGIN 0.12f

typedef __attribute__((ext_vector_type(8))) _Float16 half8;
typedef __attribute__((ext_vector_type(4))) float f32x4;
typedef unsigned long long u64;

// ---------------- embed -> fp16 [k][j][d] transpose + ||e||^2 + scratch zero ----------------
__global__ void k_prep(const float* __restrict__ embed, ushort* __restrict__ ebf,
                       float* __restrict__ enorm, int* __restrict__ hist,
                       int* __restrict__ cnt, u64* __restrict__ slots) {
    __shared__ ushort tile[DIM][130];
    __shared__ float psum[2][128];
    const int t = threadIdx.x;
    const int gb = blockIdx.x * 256 + t;          // 0..16383
#pragma unroll
    for (int i = 0; i < 4; ++i) slots[gb * 4 + i] = ~0ull;   // 65536 slots
    if (gb < K_CB * NEMB) hist[gb] = 0;
    if (gb < K_CB) cnt[gb] = 0;

    const int k = blockIdx.x >> 5;
    const int j0 = (blockIdx.x & 31) * 128;
    const int jj = t & 127, half = t >> 7;
    const float* ek = embed + (size_t)k * DIM * NEMB;
    float s = 0.f;
    for (int i = 0; i < 64; ++i) {
        int d = i * 2 + half;
        float v = ek[(size_t)d * NEMB + j0 + jj];
        s = fmaf(v, v, s);
        _Float16 h = (_Float16)v;
        tile[d][jj] = *(ushort*)&h;
    }
    psum[half][jj] = s;
    __syncthreads();
    if (t < 128) enorm[k * NEMB + j0 + t] = psum[0][t] + psum[1][t];
    ushort* outk = ebf + ((size_t)k * NEMB + j0) * DIM;
    for (int i = 0; i < 64; ++i) {
        int idx = i * 256 + t;
        int jx = idx >> 7, d = idx & 127;
        outk[(size_t)jx * DIM + d] = tile[d][jx];
    }
}

// ---------------- coarse fp16 MFMA scoring with exact (best, second, bestj) ----------------
// block (k, 128 rows), 512 threads = 8 waves as (wm 0..3 row-quarters) x (wjj 0..1 j-halves).
// Wave tile 32 rows x 64 j. A in registers (areg[2][4]); B 2x32KB double-buffered.
#define STAGE_B(dst, jt_) do { \
    _Pragma("unroll") \
    for (int it = 0; it < 4; ++it) { \
        int seg_ = it * 512 + t; \
        int row_ = seg_ >> 4; \
        int slot_ = seg_ & 15; \
        int src_ = row_ * 256 + ((slot_ * 16) ^ ((row_ & 7) << 4)); \
        const char* g_ = (const char*)ebk + (size_t)(jt_) * 32768 + src_; \
        char* l_ = (char*)(dst) + (it * 512 + (t & ~63)) * 16; \
        __builtin_amdgcn_global_load_lds( \
            (const __attribute__((address_space(1))) unsigned int*)g_, \
            (__attribute__((address_space(3))) unsigned int*)l_, 16, 0, 0); \
    } \
} while (0)

__launch_bounds__(512, 4)
__global__ void k_score(const float* __restrict__ x, const ushort* __restrict__ ebf,
                        const float* __restrict__ enorm, int* __restrict__ idxw,
                        float* __restrict__ bestv, float* __restrict__ rnorm,
                        int* __restrict__ list, int* __restrict__ cnt)
{
    __shared__ __align__(16) char smem[65536];
    __shared__ float rn[4][128];
    char* Bs0 = smem;
    char* Bs1 = smem + 32768;

    const int blk = blockIdx.x;
    const int k = blk >> 8;
    const int n0 = (blk & 255) * 128;
    const int b = n0 >> 10;
    const int hw0 = n0 & (HW - 1);
    const int t = threadIdx.x;          // 0..511
    const int lane = t & 63;
    const int w = t >> 6;               // 0..7
    const int wm = w >> 1;              // row quarter
    const int wjj = w & 1;              // j half
    const int l15 = lane & 15, l4 = lane >> 4;

    const ushort* ebk = ebf + (size_t)k * NEMB * DIM;
    const float* enk = enorm + k * NEMB;
    const float* xk = x + ((size_t)(b * CCH + k * DIM)) * HW + hw0;

    // ---- prologue: stage A [n=128][d=128] fp16 swizzled (uses both B buffers' space) ----
    {
        const int h = t & 127, q = t >> 7;   // q 0..3 (d-quarter)
        float s = 0.f;
        for (int i = 0; i < 16; ++i) {
            int d2 = q * 32 + i * 2;
            float v0 = xk[(size_t)d2 * HW + h];
            float v1 = xk[(size_t)(d2 + 1) * HW + h];
            s = fmaf(v0, v0, fmaf(v1, v1, s));
            _Float16 h0 = (_Float16)v0, h1 = (_Float16)v1;
            unsigned int u = ((unsigned int)*(ushort*)&h0) | (((unsigned int)*(ushort*)&h1) << 16);
            int byte = h * 256 + ((d2 * 2) ^ ((h & 15) << 4));
            *(unsigned int*)(smem + byte) = u;
        }
        rn[q][h] = s;
    }
    __syncthreads();
    if (t < 128) rnorm[k * NPK + n0 + t] = rn[0][t] + rn[1][t] + rn[2][t] + rn[3][t];

    // ---- A-frags to registers: 2 mf x 4 kk (this wave's 32 rows) ----
    half8 areg[2][4];
#pragma unroll
    for (int mf = 0; mf < 2; ++mf)
#pragma unroll
        for (int kk = 0; kk < 4; ++kk) {
            int row = wm * 32 + mf * 16 + l15;
            int byte = row * 256 + ((kk * 64 + l4 * 16) ^ ((row & 15) << 4));
            areg[mf][kk] = *(const half8*)(smem + byte);
        }
    __syncthreads();   // A reads done before B staging overwrites

    STAGE_B(Bs0, 0);
    __syncthreads();   // Bs0 ready

    float best[8], second[8];
    int bestj[8];
#pragma unroll
    for (int i = 0; i < 8; ++i) { best[i] = 3.4e38f; second[i] = 3.4e38f; bestj[i] = 0; }

    for (int jt = 0; jt < 32; ++jt) {
        const char* Bc = (jt & 1) ? Bs1 : Bs0;
        char* Bn = (jt & 1) ? Bs0 : Bs1;
        if (jt < 31) STAGE_B(Bn, jt + 1);

        f32x4 acc[2][4];
#pragma unroll
        for (int mf = 0; mf < 2; ++mf)
#pragma unroll
            for (int jf = 0; jf < 4; ++jf) acc[mf][jf] = (f32x4){0.f, 0.f, 0.f, 0.f};

#pragma unroll
        for (int kk = 0; kk < 4; ++kk) {
            half8 bb[4];
#pragma unroll
            for (int jf = 0; jf < 4; ++jf) {
                int row = wjj * 64 + jf * 16 + l15;
                int byte = row * 256 + ((kk * 64 + l4 * 16) ^ ((row & 7) << 4));
                bb[jf] = *(const half8*)(Bc + byte);
            }
#pragma unroll
            for (int mf = 0; mf < 2; ++mf)
#pragma unroll
                for (int jf = 0; jf < 4; ++jf)
                    acc[mf][jf] = __builtin_amdgcn_mfma_f32_16x16x32_f16(areg[mf][kk], bb[jf], acc[mf][jf], 0, 0, 0);
        }

        // ---- epilogue: exact (best, second, bestj) over this wave's 32r x 64j ----
#pragma unroll
        for (int jf = 0; jf < 4; ++jf) {
            const int j = jt * 128 + wjj * 64 + jf * 16 + l15;
            const float en = enk[j];
#pragma unroll
            for (int mf = 0; mf < 2; ++mf)
#pragma unroll
                for (int r = 0; r < 4; ++r) {
                    int ti = mf * 4 + r;
                    float sv = fmaf(-2.f, acc[mf][jf][r], en);
                    second[ti] = fminf(fmaxf(sv, best[ti]), second[ti]);
                    bool lt = sv < best[ti];
                    bestj[ti] = lt ? j : bestj[ti];
                    best[ti] = fminf(best[ti], sv);
                }
        }
        __syncthreads();   // next tile's staged buffer ready
    }

    // ---- merge across the 16 j-lanes sharing each row ----
#pragma unroll
    for (int off = 1; off < 16; off <<= 1) {
#pragma unroll
        for (int ti = 0; ti < 8; ++ti) {
            float ob = __shfl_xor(best[ti], off);
            float os = __shfl_xor(second[ti], off);
            int oj = __shfl_xor(bestj[ti], off);
            float ns = fminf(fmaxf(best[ti], ob), fminf(second[ti], os));
            bool take = (ob < best[ti]) || (ob == best[ti] && oj < bestj[ti]);
            bestj[ti] = take ? oj : bestj[ti];
            best[ti] = fminf(best[ti], ob);
            second[ti] = ns;
        }
    }

    // ---- merge the two wjj waves per row via LDS ----
    __syncthreads();
    float* tb = (float*)smem;          // [128][2]
    float* ts = tb + 256;              // [128][2]
    int*   tc = (int*)(ts + 256);      // [128][2]
    if (l15 == 0) {
#pragma unroll
        for (int ti = 0; ti < 8; ++ti) {
            int mf = ti >> 2, r = ti & 3;
            int row = wm * 32 + mf * 16 + l4 * 4 + r;
            tb[row * 2 + wjj] = best[ti];
            ts[row * 2 + wjj] = second[ti];
            tc[row * 2 + wjj] = bestj[ti];
        }
    }
    __syncthreads();
    if (t < 128) {
        float b0 = tb[t * 2], b1 = tb[t * 2 + 1];
        float s0 = ts[t * 2], s1 = ts[t * 2 + 1];
        int   j0 = tc[t * 2], j1 = tc[t * 2 + 1];
        float nb = fminf(b0, b1);
        float ns = fminf(fmaxf(b0, b1), fminf(s0, s1));
        bool take1 = (b1 < b0) || (b1 == b0 && j1 < j0);
        int   nj = take1 ? j1 : j0;
        int gidx = k * NPK + n0 + t;
        idxw[gidx] = nj;
        bestv[gidx] = nb;
        if (ns - nb < MARGIN) {
            int p = atomicAdd(&cnt[k], 1);
            list[k * NPK + p] = gidx;
        }
    }
}

// ---------------- exact fp32 rescore: (4-row chunk) x (256-j slab) items ----------------
__global__ void k_rescore(const float* __restrict__ x, const float* __restrict__ embed,
                          const float* __restrict__ enorm, const int* __restrict__ list,
                          const int* __restrict__ cnt, u64* __restrict__ slots)
{
    __shared__ float xr[4][128];
    __shared__ u64 part[4][4];
    const int t = threadIdx.x;
    const int lane = t & 63, wv = t >> 6;
    const int c0 = cnt[0], c1 = cnt[1];
    const int items0 = ((c0 + 3) >> 2) * 16;
    const int items1 = ((c1 + 3) >> 2) * 16;
    const int total = items0 + items1;

    for (int item = blockIdx.x; item < total; item += gridDim.x) {
        int k, c, sl, ck;
        if (item < items0) { k = 0; c = item >> 4; sl = item & 15; ck = c0; }
        else { int it = item - items0; k = 1; c = it >> 4; sl = it & 15; ck = c1; }
        const int base = c * 4;
        const int cn = min(4, ck - base);
        __syncthreads();   // xr/part reuse safety
        for (int ii = t; ii < cn * 128; ii += 256) {
            int ri = ii >> 7, d = ii & 127;
            int gidx = list[k * NPK + base + ri];
            int n = gidx & (NPK - 1);
            int bb = n >> 10, hw = n & 1023;
            xr[ri][d] = x[((size_t)(bb * CCH + k * DIM + d)) * HW + hw];
        }
        __syncthreads();

        const int j = sl * 256 + t;
        float dot[4];
#pragma unroll
        for (int ri = 0; ri < 4; ++ri) dot[ri] = 0.f;
        const float* ek = embed + (size_t)k * DIM * NEMB + j;
        for (int d = 0; d < DIM; ++d) {
            float ev = ek[(size_t)d * NEMB];
#pragma unroll
            for (int ri = 0; ri < 4; ++ri) dot[ri] = fmaf(xr[ri][d], ev, dot[ri]);
        }
        const float en = enorm[k * NEMB + j];
        u64 key[4];
#pragma unroll
        for (int ri = 0; ri < 4; ++ri) {
            float sc = fmaf(-2.f, dot[ri], en);
            unsigned int bits = __float_as_uint(sc);
            unsigned int u = (sc >= 0.f) ? (bits | 0x80000000u) : ~bits;
            key[ri] = ((u64)u << 32) | (unsigned int)j;
        }
#pragma unroll
        for (int off = 32; off; off >>= 1) {
#pragma unroll
            for (int ri = 0; ri < 4; ++ri) {
                u64 o = __shfl_xor(key[ri], off);
                key[ri] = o < key[ri] ? o : key[ri];
            }
        }
        if (lane == 0) {
#pragma unroll
            for (int ri = 0; ri < 4; ++ri) part[wv][ri] = key[ri];
        }
        __syncthreads();
        if (t < 16) {
            int ri = t >> 2, w2 = t & 3;
            u64 kk = part[w2][ri];
            u64 o = __shfl_xor(kk, 1); kk = o < kk ? o : kk;
            o = __shfl_xor(kk, 2);     kk = o < kk ? o : kk;
            if (w2 == 0 && ri < cn)
                atomicMin(&slots[k * NPK + base + ri], kk);
        }
    }
}

// ---------------- write rescored winners + exact scores back ----------------
__global__ void k_fixup(const int* __restrict__ list, const int* __restrict__ cnt,
                        const u64* __restrict__ slots, int* __restrict__ idxw,
                        float* __restrict__ bestv) {
    int g = blockIdx.x * 256 + threadIdx.x;
#pragma unroll
    for (int k = 0; k < K_CB; ++k)
        if (g < cnt[k]) {
            u64 sl = slots[k * NPK + g];
            int gidx = list[k * NPK + g];
            idxw[gidx] = (int)(sl & 0xFFFFFFFFu);
            unsigned int u = (unsigned int)(sl >> 32);
            unsigned int bits = (u & 0x80000000u) ? (u & 0x7FFFFFFFu) : ~u;
            bestv[gidx] = __uint_as_float(bits);
        }
}

// ---------------- gather z_q + argf/hist (emit fused) ----------------
__global__ void k_gather(const float* __restrict__ embed, const int* __restrict__ idx,
                         float* __restrict__ zq, float* __restrict__ argf,
                         int* __restrict__ hist)
{
    const int blk = blockIdx.x;           // k*4096 + b*128 + d
    const int k = blk >> 12;
    const int b = (blk >> 7) & 31;
    const int d = blk & 127;
    const float* erow = embed + ((size_t)k * DIM + d) * NEMB;
    const int* idxr = idx + k * NPK + b * HW;
    float* zr = zq + ((size_t)b * CCH + (size_t)k * DIM + d) * HW;
    const int t = threadIdx.x;
#pragma unroll
    for (int i = 0; i < 4; ++i) {
        int h = i * 256 + t;
        int j = idxr[h];
        zr[h] = erow[j];
        if (d == 0) {
            argf[k * NPK + b * HW + h] = (float)j;
            atomicAdd(&hist[k * NEMB + j], 1);
        }
    }
}

// ---------------- finalize diffs (rnorm + bestv) + perplexity ----------------
__global__ void k_final(const float* __restrict__ rnorm, const float* __restrict__ bestv,
                        const int* __restrict__ hist, float* __restrict__ diffs,
                        float* __restrict__ ppls)
{
    const int k = blockIdx.x;
    const int t = threadIdx.x;
    __shared__ float red[256];
    float s = 0.f;
    for (int i = t; i < NPK; i += 256)
        s += rnorm[k * NPK + i] + bestv[k * NPK + i];
    red[t] = s;
    __syncthreads();
    for (int off = 128; off > 0; off >>= 1) {
        if (t < off) red[t] += red[t + off];
        __syncthreads();
    }
    if (t == 0) diffs[k] = red[0] / (float)((size_t)NPK * DIM);
    __syncthreads();
    float s2 = 0.f;
    for (int i = t; i < NEMB; i += 256) {
        float p = (float)hist[k * NEMB + i] * (1.0f / (float)NPK);
        s2 += p * logf(p + 1e-10f);
    }
    red[t] = s2;
    __syncthreads();
    for (int off = 128; off > 0; off >>= 1) {
        if (t < off) red[t] += red[t + off];
        __syncthreads();
    }
    if (t == 0) ppls[k] = expf(-red[0]);
}

extern "C" void kernel_launch(void* const* d_in, const int* in_sizes, int n_in,
                              void* d_out, int out_size, void* d_ws, size_t ws_size,
                              hipStream_t stream) {
    const float* x = (const float*)d_in[0];       // [32,256,32,32]
    const float* embed = (const float*)d_in[1];   // [2,128,4096]
    float* out = (float*)d_out;
    float* zq    = out;                 // 8388608
    float* diffs = out + 8388608;       // 2
    float* argf  = out + 8388610;       // 65536 ([K,B,H,W] as float)
    float* ppls  = out + 8454146;       // 2

    char* W = (char*)d_ws;
    ushort* ebf   = (ushort*)W;                    // 2,097,152 : embedT fp16 [2][4096][128]
    float* enorm  = (float*)(W + 2097152);         // 32768
    int*   idx    = (int*)(W + 2129920);           // 262144
    int*   hist   = (int*)(W + 2392064);           // 32768
    float* rnorm  = (float*)(W + 2424832);         // 262144
    float* bestv  = (float*)(W + 2686976);         // 262144
    int*   list   = (int*)(W + 2949120);           // 262144
    int*   cnt    = (int*)(W + 3211264);           // 64
    u64*   slots  = (u64*)(W + 3211328);           // 524288 -> ends ~3.74 MB

    k_prep   <<<64,   256, 0, stream>>>(embed, ebf, enorm, hist, cnt, slots);
    k_score  <<<512,  512, 0, stream>>>(x, ebf, enorm, idx, bestv, rnorm, list, cnt);
    k_rescore<<<4096, 256, 0, stream>>>(x, embed, enorm, list, cnt, slots);
    k_fixup  <<<128,  256, 0, stream>>>(list, cnt, slots, idx, bestv);
    k_gather <<<8192, 256, 0, stream>>>(embed, idx, zq, argf, hist);
    k_final  <<<2,    256, 0, stream>>>(rnorm, bestv, hist, diffs, ppls);
}

// Round 8
// 232.262 us; speedup vs baseline: 2.7471x; 1.0166x over previous
//
#include <hip/hip_runtime.h>
#include <hip/hip_bf16.h>
#include <math.h>

#define K_CB 2
#define DIM 128
#define NEMB 4096
#define HW 1024
#define NPK 32768
#define CCH 256
#define MARGIN 0.12f

typedef __attribute__((ext_vector_type(8))) _Float16 half8;
typedef __attribute__((ext_vector_type(4))) float f32x4;
typedef unsigned long long u64;

// ---------------- embed -> fp16 [k][j][d] transpose + ||e||^2 + scratch zero ----------------
__global__ void k_prep(const float* __restrict__ embed, ushort* __restrict__ ebf,
                       float* __restrict__ enorm, int* __restrict__ hist,
                       int* __restrict__ cnt, u64* __restrict__ slots) {
    __shared__ ushort tile[DIM][130];
    __shared__ float psum[2][128];
    const int t = threadIdx.x;
    const int gb = blockIdx.x * 256 + t;          // 0..16383
#pragma unroll
    for (int i = 0; i < 4; ++i) slots[gb * 4 + i] = ~0ull;   // 65536 slots
    if (gb < K_CB * NEMB) hist[gb] = 0;
    if (gb < K_CB) cnt[gb] = 0;

    const int k = blockIdx.x >> 5;
    const int j0 = (blockIdx.x & 31) * 128;
    const int jj = t & 127, half = t >> 7;
    const float* ek = embed + (size_t)k * DIM * NEMB;
    float s = 0.f;
    for (int i = 0; i < 64; ++i) {
        int d = i * 2 + half;
        float v = ek[(size_t)d * NEMB + j0 + jj];
        s = fmaf(v, v, s);
        _Float16 h = (_Float16)v;
        tile[d][jj] = *(ushort*)&h;
    }
    psum[half][jj] = s;
    __syncthreads();
    if (t < 128) enorm[k * NEMB + j0 + t] = psum[0][t] + psum[1][t];
    ushort* outk = ebf + ((size_t)k * NEMB + j0) * DIM;
    for (int i = 0; i < 64; ++i) {
        int idx = i * 256 + t;
        int jx = idx >> 7, d = idx & 127;
        outk[(size_t)jx * DIM + d] = tile[d][jx];
    }
}

// ---------------- coarse fp16 MFMA scoring with exact (best, second, bestj) ----------------
// block (k, 128 rows), 512 threads = 8 waves as (wm 0..3 row-quarters) x (wjj 0..1 j-halves).
// Wave tile 32 rows x 64 j. A in registers (areg[2][4]); B 2x32KB double-buffered.
// XOR swizzle MUST be the 4-bit field (row&15)<<4: 3-bit (&7) makes lanes l15 and
// l15+8 collide on the same bank (2048B apart) -> 2x serialization (round-7 regression).
#define STAGE_B(dst, jt_) do { \
    _Pragma("unroll") \
    for (int it = 0; it < 4; ++it) { \
        int seg_ = it * 512 + t; \
        int row_ = seg_ >> 4; \
        int slot_ = seg_ & 15; \
        int src_ = row_ * 256 + ((slot_ * 16) ^ ((row_ & 15) << 4)); \
        const char* g_ = (const char*)ebk + (size_t)(jt_) * 32768 + src_; \
        char* l_ = (char*)(dst) + (it * 512 + (t & ~63)) * 16; \
        __builtin_amdgcn_global_load_lds( \
            (const __attribute__((address_space(1))) unsigned int*)g_, \
            (__attribute__((address_space(3))) unsigned int*)l_, 16, 0, 0); \
    } \
} while (0)

__launch_bounds__(512, 4)
__global__ void k_score(const float* __restrict__ x, const ushort* __restrict__ ebf,
                        const float* __restrict__ enorm, int* __restrict__ idxw,
                        float* __restrict__ bestv, float* __restrict__ rnorm,
                        int* __restrict__ list, int* __restrict__ cnt)
{
    __shared__ __align__(16) char smem[65536];
    __shared__ float rn[4][128];
    char* Bs0 = smem;
    char* Bs1 = smem + 32768;

    const int blk = blockIdx.x;
    const int k = blk >> 8;
    const int n0 = (blk & 255) * 128;
    const int b = n0 >> 10;
    const int hw0 = n0 & (HW - 1);
    const int t = threadIdx.x;          // 0..511
    const int lane = t & 63;
    const int w = t >> 6;               // 0..7
    const int wm = w >> 1;              // row quarter
    const int wjj = w & 1;              // j half
    const int l15 = lane & 15, l4 = lane >> 4;

    const ushort* ebk = ebf + (size_t)k * NEMB * DIM;
    const float* enk = enorm + k * NEMB;
    const float* xk = x + ((size_t)(b * CCH + k * DIM)) * HW + hw0;

    // ---- prologue: stage A [n=128][d=128] fp16 swizzled (uses both B buffers' space) ----
    {
        const int h = t & 127, q = t >> 7;   // q 0..3 (d-quarter)
        float s = 0.f;
        for (int i = 0; i < 16; ++i) {
            int d2 = q * 32 + i * 2;
            float v0 = xk[(size_t)d2 * HW + h];
            float v1 = xk[(size_t)(d2 + 1) * HW + h];
            s = fmaf(v0, v0, fmaf(v1, v1, s));
            _Float16 h0 = (_Float16)v0, h1 = (_Float16)v1;
            unsigned int u = ((unsigned int)*(ushort*)&h0) | (((unsigned int)*(ushort*)&h1) << 16);
            int byte = h * 256 + ((d2 * 2) ^ ((h & 15) << 4));
            *(unsigned int*)(smem + byte) = u;
        }
        rn[q][h] = s;
    }
    __syncthreads();
    if (t < 128) rnorm[k * NPK + n0 + t] = rn[0][t] + rn[1][t] + rn[2][t] + rn[3][t];

    // ---- A-frags to registers: 2 mf x 4 kk (this wave's 32 rows) ----
    half8 areg[2][4];
#pragma unroll
    for (int mf = 0; mf < 2; ++mf)
#pragma unroll
        for (int kk = 0; kk < 4; ++kk) {
            int row = wm * 32 + mf * 16 + l15;
            int byte = row * 256 + ((kk * 64 + l4 * 16) ^ ((row & 15) << 4));
            areg[mf][kk] = *(const half8*)(smem + byte);
        }
    __syncthreads();   // A reads done before B staging overwrites

    STAGE_B(Bs0, 0);
    __syncthreads();   // Bs0 ready

    float best[8], second[8];
    int bestj[8];
#pragma unroll
    for (int i = 0; i < 8; ++i) { best[i] = 3.4e38f; second[i] = 3.4e38f; bestj[i] = 0; }

    for (int jt = 0; jt < 32; ++jt) {
        const char* Bc = (jt & 1) ? Bs1 : Bs0;
        char* Bn = (jt & 1) ? Bs0 : Bs1;
        if (jt < 31) STAGE_B(Bn, jt + 1);

        f32x4 acc[2][4];
#pragma unroll
        for (int mf = 0; mf < 2; ++mf)
#pragma unroll
            for (int jf = 0; jf < 4; ++jf) acc[mf][jf] = (f32x4){0.f, 0.f, 0.f, 0.f};

#pragma unroll
        for (int kk = 0; kk < 4; ++kk) {
            half8 bb[4];
#pragma unroll
            for (int jf = 0; jf < 4; ++jf) {
                int row = wjj * 64 + jf * 16 + l15;
                int byte = row * 256 + ((kk * 64 + l4 * 16) ^ ((row & 15) << 4));
                bb[jf] = *(const half8*)(Bc + byte);
            }
#pragma unroll
            for (int mf = 0; mf < 2; ++mf)
#pragma unroll
                for (int jf = 0; jf < 4; ++jf)
                    acc[mf][jf] = __builtin_amdgcn_mfma_f32_16x16x32_f16(areg[mf][kk], bb[jf], acc[mf][jf], 0, 0, 0);
        }

        // ---- epilogue: exact (best, second, bestj) over this wave's 32r x 64j ----
#pragma unroll
        for (int jf = 0; jf < 4; ++jf) {
            const int j = jt * 128 + wjj * 64 + jf * 16 + l15;
            const float en = enk[j];
#pragma unroll
            for (int mf = 0; mf < 2; ++mf)
#pragma unroll
                for (int r = 0; r < 4; ++r) {
                    int ti = mf * 4 + r;
                    float sv = fmaf(-2.f, acc[mf][jf][r], en);
                    second[ti] = fminf(fmaxf(sv, best[ti]), second[ti]);
                    bool lt = sv < best[ti];
                    bestj[ti] = lt ? j : bestj[ti];
                    best[ti] = fminf(best[ti], sv);
                }
        }
        __syncthreads();   // next tile's staged buffer ready
    }

    // ---- merge across the 16 j-lanes sharing each row ----
#pragma unroll
    for (int off = 1; off < 16; off <<= 1) {
#pragma unroll
        for (int ti = 0; ti < 8; ++ti) {
            float ob = __shfl_xor(best[ti], off);
            float os = __shfl_xor(second[ti], off);
            int oj = __shfl_xor(bestj[ti], off);
            float ns = fminf(fmaxf(best[ti], ob), fminf(second[ti], os));
            bool take = (ob < best[ti]) || (ob == best[ti] && oj < bestj[ti]);
            bestj[ti] = take ? oj : bestj[ti];
            best[ti] = fminf(best[ti], ob);
            second[ti] = ns;
        }
    }

    // ---- merge the two wjj waves per row via LDS ----
    __syncthreads();
    float* tb = (float*)smem;          // [128][2]
    float* ts = tb + 256;              // [128][2]
    int*   tc = (int*)(ts + 256);      // [128][2]
    if (l15 == 0) {
#pragma unroll
        for (int ti = 0; ti < 8; ++ti) {
            int mf = ti >> 2, r = ti & 3;
            int row = wm * 32 + mf * 16 + l4 * 4 + r;
            tb[row * 2 + wjj] = best[ti];
            ts[row * 2 + wjj] = second[ti];
            tc[row * 2 + wjj] = bestj[ti];
        }
    }
    __syncthreads();
    if (t < 128) {
        float b0 = tb[t * 2], b1 = tb[t * 2 + 1];
        float s0 = ts[t * 2], s1 = ts[t * 2 + 1];
        int   j0 = tc[t * 2], j1 = tc[t * 2 + 1];
        float nb = fminf(b0, b1);
        float ns = fminf(fmaxf(b0, b1), fminf(s0, s1));
        bool take1 = (b1 < b0) || (b1 == b0 && j1 < j0);
        int   nj = take1 ? j1 : j0;
        int gidx = k * NPK + n0 + t;
        idxw[gidx] = nj;
        bestv[gidx] = nb;
        if (ns - nb < MARGIN) {
            int p = atomicAdd(&cnt[k], 1);
            list[k * NPK + p] = gidx;
        }
    }
}

// ---------------- exact fp32 rescore: (4-row chunk) x (256-j slab) items ----------------
__global__ void k_rescore(const float* __restrict__ x, const float* __restrict__ embed,
                          const float* __restrict__ enorm, const int* __restrict__ list,
                          const int* __restrict__ cnt, u64* __restrict__ slots)
{
    __shared__ float xr[4][128];
    __shared__ u64 part[4][4];
    const int t = threadIdx.x;
    const int lane = t & 63, wv = t >> 6;
    const int c0 = cnt[0], c1 = cnt[1];
    const int items0 = ((c0 + 3) >> 2) * 16;
    const int items1 = ((c1 + 3) >> 2) * 16;
    const int total = items0 + items1;

    for (int item = blockIdx.x; item < total; item += gridDim.x) {
        int k, c, sl, ck;
        if (item < items0) { k = 0; c = item >> 4; sl = item & 15; ck = c0; }
        else { int it = item - items0; k = 1; c = it >> 4; sl = it & 15; ck = c1; }
        const int base = c * 4;
        const int cn = min(4, ck - base);
        __syncthreads();   // xr/part reuse safety
        for (int ii = t; ii < cn * 128; ii += 256) {
            int ri = ii >> 7, d = ii & 127;
            int gidx = list[k * NPK + base + ri];
            int n = gidx & (NPK - 1);
            int bb = n >> 10, hw = n & 1023;
            xr[ri][d] = x[((size_t)(bb * CCH + k * DIM + d)) * HW + hw];
        }
        __syncthreads();

        const int j = sl * 256 + t;
        float dot[4];
#pragma unroll
        for (int ri = 0; ri < 4; ++ri) dot[ri] = 0.f;
        const float* ek = embed + (size_t)k * DIM * NEMB + j;
        for (int d = 0; d < DIM; ++d) {
            float ev = ek[(size_t)d * NEMB];
#pragma unroll
            for (int ri = 0; ri < 4; ++ri) dot[ri] = fmaf(xr[ri][d], ev, dot[ri]);
        }
        const float en = enorm[k * NEMB + j];
        u64 key[4];
#pragma unroll
        for (int ri = 0; ri < 4; ++ri) {
            float sc = fmaf(-2.f, dot[ri], en);
            unsigned int bits = __float_as_uint(sc);
            unsigned int u = (sc >= 0.f) ? (bits | 0x80000000u) : ~bits;
            key[ri] = ((u64)u << 32) | (unsigned int)j;
        }
#pragma unroll
        for (int off = 32; off; off >>= 1) {
#pragma unroll
            for (int ri = 0; ri < 4; ++ri) {
                u64 o = __shfl_xor(key[ri], off);
                key[ri] = o < key[ri] ? o : key[ri];
            }
        }
        if (lane == 0) {
#pragma unroll
            for (int ri = 0; ri < 4; ++ri) part[wv][ri] = key[ri];
        }
        __syncthreads();
        if (t < 16) {
            int ri = t >> 2, w2 = t & 3;
            u64 kk = part[w2][ri];
            u64 o = __shfl_xor(kk, 1); kk = o < kk ? o : kk;
            o = __shfl_xor(kk, 2);     kk = o < kk ? o : kk;
            if (w2 == 0 && ri < cn)
                atomicMin(&slots[k * NPK + base + ri], kk);
        }
    }
}

// ---------------- write rescored winners + exact scores back ----------------
__global__ void k_fixup(const int* __restrict__ list, const int* __restrict__ cnt,
                        const u64* __restrict__ slots, int* __restrict__ idxw,
                        float* __restrict__ bestv) {
    int g = blockIdx.x * 256 + threadIdx.x;
#pragma unroll
    for (int k = 0; k < K_CB; ++k)
        if (g < cnt[k]) {
            u64 sl = slots[k * NPK + g];
            int gidx = list[k * NPK + g];
            idxw[gidx] = (int)(sl & 0xFFFFFFFFu);
            unsigned int u = (unsigned int)(sl >> 32);
            unsigned int bits = (u & 0x80000000u) ? (u & 0x7FFFFFFFu) : ~u;
            bestv[gidx] = __uint_as_float(bits);
        }
}

// ---------------- gather z_q + argf/hist (emit fused) ----------------
__global__ void k_gather(const float* __restrict__ embed, const int* __restrict__ idx,
                         float* __restrict__ zq, float* __restrict__ argf,
                         int* __restrict__ hist)
{
    const int blk = blockIdx.x;           // k*4096 + b*128 + d
    const int k = blk >> 12;
    const int b = (blk >> 7) & 31;
    const int d = blk & 127;
    const float* erow = embed + ((size_t)k * DIM + d) * NEMB;
    const int* idxr = idx + k * NPK + b * HW;
    float* zr = zq + ((size_t)b * CCH + (size_t)k * DIM + d) * HW;
    const int t = threadIdx.x;
#pragma unroll
    for (int i = 0; i < 4; ++i) {
        int h = i * 256 + t;
        int j = idxr[h];
        zr[h] = erow[j];
        if (d == 0) {
            argf[k * NPK + b * HW + h] = (float)j;
            atomicAdd(&hist[k * NEMB + j], 1);
        }
    }
}

// ---------------- finalize diffs (rnorm + bestv) + perplexity ----------------
__global__ void k_final(const float* __restrict__ rnorm, const float* __restrict__ bestv,
                        const int* __restrict__ hist, float* __restrict__ diffs,
                        float* __restrict__ ppls)
{
    const int k = blockIdx.x;
    const int t = threadIdx.x;
    __shared__ float red[256];
    float s = 0.f;
    for (int i = t; i < NPK; i += 256)
        s += rnorm[k * NPK + i] + bestv[k * NPK + i];
    red[t] = s;
    __syncthreads();
    for (int off = 128; off > 0; off >>= 1) {
        if (t < off) red[t] += red[t + off];
        __syncthreads();
    }
    if (t == 0) diffs[k] = red[0] / (float)((size_t)NPK * DIM);
    __syncthreads();
    float s2 = 0.f;
    for (int i = t; i < NEMB; i += 256) {
        float p = (float)hist[k * NEMB + i] * (1.0f / (float)NPK);
        s2 += p * logf(p + 1e-10f);
    }
    red[t] = s2;
    __syncthreads();
    for (int off = 128; off > 0; off >>= 1) {
        if (t < off) red[t] += red[t + off];
        __syncthreads();
    }
    if (t == 0) ppls[k] = expf(-red[0]);
}

extern "C" void kernel_launch(void* const* d_in, const int* in_sizes, int n_in,
                              void* d_out, int out_size, void* d_ws, size_t ws_size,
                              hipStream_t stream) {
    const float* x = (const float*)d_in[0];       // [32,256,32,32]
    const float* embed = (const float*)d_in[1];   // [2,128,4096]
    float* out = (float*)d_out;
    float* zq    = out;                 // 8388608
    float* diffs = out + 8388608;       // 2
    float* argf  = out + 8388610;       // 65536 ([K,B,H,W] as float)
    float* ppls  = out + 8454146;       // 2

    char* W = (char*)d_ws;
    ushort* ebf   = (ushort*)W;                    // 2,097,152 : embedT fp16 [2][4096][128]
    float* enorm  = (float*)(W + 2097152);         // 32768
    int*   idx    = (int*)(W + 2129920);           // 262144
    int*   hist   = (int*)(W + 2392064);           // 32768
    float* rnorm  = (float*)(W + 2424832);         // 262144
    float* bestv  = (float*)(W + 2686976);         // 262144
    int*   list   = (int*)(W + 2949120);           // 262144
    int*   cnt    = (int*)(W + 3211264);           // 64
    u64*   slots  = (u64*)(W + 3211328);           // 524288 -> ends ~3.74 MB

    k_prep   <<<64,   256, 0, stream>>>(embed, ebf, enorm, hist, cnt, slots);
    k_score  <<<512,  512, 0, stream>>>(x, ebf, enorm, idx, bestv, rnorm, list, cnt);
    k_rescore<<<4096, 256, 0, stream>>>(x, embed, enorm, list, cnt, slots);
    k_fixup  <<<128,  256, 0, stream>>>(list, cnt, slots, idx, bestv);
    k_gather <<<8192, 256, 0, stream>>>(embed, idx, zq, argf, hist);
    k_final  <<<2,    256, 0, stream>>>(rnorm, bestv, hist, diffs, ppls);
}

// Round 9
// 195.003 us; speedup vs baseline: 3.2720x; 1.1911x over previous
//
#include <hip/hip_runtime.h>
#include <hip/hip_bf16.h>
#include <math.h>

#define K_CB 2
#define DIM 128
#define NEMB 4096
#define HW 1024
#define NPK 32768
#define CCH 256
#define MARGIN 0.13f

typedef __attribute__((ext_vector_type(8))) _Float16 half8;
typedef __attribute__((ext_vector_type(4))) float f32x4;
typedef unsigned long long u64;

// ---------------- embed -> fp16 [k][j][d] transpose + ||e||^2 (+512 copy) + scratch zero ----------------
__global__ void k_prep(const float* __restrict__ embed, ushort* __restrict__ ebf,
                       float* __restrict__ enorm, float* __restrict__ en512,
                       int* __restrict__ hist, int* __restrict__ cnt, u64* __restrict__ slots) {
    __shared__ ushort tile[DIM][130];
    __shared__ float psum[2][128];
    const int t = threadIdx.x;
    const int gb = blockIdx.x * 256 + t;          // 0..16383
#pragma unroll
    for (int i = 0; i < 4; ++i) slots[gb * 4 + i] = ~0ull;   // 65536 slots
    if (gb < K_CB * NEMB) hist[gb] = 0;
    if (gb < K_CB) cnt[gb] = 0;

    const int k = blockIdx.x >> 5;
    const int j0 = (blockIdx.x & 31) * 128;
    const int jj = t & 127, half = t >> 7;
    const float* ek = embed + (size_t)k * DIM * NEMB;
    float s = 0.f;
    for (int i = 0; i < 64; ++i) {
        int d = i * 2 + half;
        float v = ek[(size_t)d * NEMB + j0 + jj];
        s = fmaf(v, v, s);
        _Float16 h = (_Float16)v;
        tile[d][jj] = *(ushort*)&h;
    }
    psum[half][jj] = s;
    __syncthreads();
    if (t < 128) {
        float e = psum[0][t] + psum[1][t];
        enorm[k * NEMB + j0 + t] = e;           // exact, for rescore
        en512[k * NEMB + j0 + t] = e + 512.f;   // shifted, for coarse packed scoring
    }
    ushort* outk = ebf + ((size_t)k * NEMB + j0) * DIM;
    for (int i = 0; i < 64; ++i) {
        int idx = i * 256 + t;
        int jx = idx >> 7, d = idx & 127;
        outk[(size_t)jx * DIM + d] = tile[d][jx];
    }
}

// ---------------- coarse fp16 MFMA scoring, packed (score|jloc) epilogue ----------------
// block (k, 128 rows), 512 threads = 8 waves as (wm 0..3 row-quarters) x (wjj 0..1 j-halves).
// Wave tile 32 rows x 64 j. A in registers; B 2x32KB double-buffered; 4-bit XOR swizzle.
// Scores shifted +512 (positive) -> low 7 mantissa bits carry jloc (perturb <= 0.008).
#define STAGE_B(dst, jt_) do { \
    _Pragma("unroll") \
    for (int it = 0; it < 4; ++it) { \
        int seg_ = it * 512 + t; \
        int row_ = seg_ >> 4; \
        int slot_ = seg_ & 15; \
        int src_ = row_ * 256 + ((slot_ * 16) ^ ((row_ & 15) << 4)); \
        const char* g_ = (const char*)ebk + (size_t)(jt_) * 32768 + src_; \
        char* l_ = (char*)(dst) + (it * 512 + (t & ~63)) * 16; \
        __builtin_amdgcn_global_load_lds( \
            (const __attribute__((address_space(1))) unsigned int*)g_, \
            (__attribute__((address_space(3))) unsigned int*)l_, 16, 0, 0); \
    } \
} while (0)

__launch_bounds__(512, 4)
__global__ void k_score(const float* __restrict__ x, const ushort* __restrict__ ebf,
                        const float* __restrict__ en512, int* __restrict__ idxw,
                        float* __restrict__ bestv, float* __restrict__ rnorm,
                        int* __restrict__ list, int* __restrict__ cnt)
{
    __shared__ __align__(16) char smem[65536];
    __shared__ float rn[4][128];
    char* Bs0 = smem;
    char* Bs1 = smem + 32768;

    const int blk = blockIdx.x;
    const int k = blk >> 8;
    const int n0 = (blk & 255) * 128;
    const int b = n0 >> 10;
    const int hw0 = n0 & (HW - 1);
    const int t = threadIdx.x;          // 0..511
    const int lane = t & 63;
    const int w = t >> 6;               // 0..7
    const int wm = w >> 1;              // row quarter
    const int wjj = w & 1;              // j half
    const int l15 = lane & 15, l4 = lane >> 4;

    const ushort* ebk = ebf + (size_t)k * NEMB * DIM;
    const float* enk = en512 + k * NEMB;
    const float* xk = x + ((size_t)(b * CCH + k * DIM)) * HW + hw0;

    // ---- prologue: stage A [n=128][d=128] fp16 swizzled (uses both B buffers' space) ----
    {
        const int h = t & 127, q = t >> 7;   // q 0..3 (d-quarter)
        float s = 0.f;
        for (int i = 0; i < 16; ++i) {
            int d2 = q * 32 + i * 2;
            float v0 = xk[(size_t)d2 * HW + h];
            float v1 = xk[(size_t)(d2 + 1) * HW + h];
            s = fmaf(v0, v0, fmaf(v1, v1, s));
            _Float16 h0 = (_Float16)v0, h1 = (_Float16)v1;
            unsigned int u = ((unsigned int)*(ushort*)&h0) | (((unsigned int)*(ushort*)&h1) << 16);
            int byte = h * 256 + ((d2 * 2) ^ ((h & 15) << 4));
            *(unsigned int*)(smem + byte) = u;
        }
        rn[q][h] = s;
    }
    __syncthreads();
    if (t < 128) rnorm[k * NPK + n0 + t] = rn[0][t] + rn[1][t] + rn[2][t] + rn[3][t];

    // ---- A-frags to registers: 2 mf x 4 kk (this wave's 32 rows) ----
    half8 areg[2][4];
#pragma unroll
    for (int mf = 0; mf < 2; ++mf)
#pragma unroll
        for (int kk = 0; kk < 4; ++kk) {
            int row = wm * 32 + mf * 16 + l15;
            int byte = row * 256 + ((kk * 64 + l4 * 16) ^ ((row & 15) << 4));
            areg[mf][kk] = *(const half8*)(smem + byte);
        }
    __syncthreads();   // A reads done before B staging overwrites

    STAGE_B(Bs0, 0);
    __syncthreads();   // Bs0 ready

    const f32x4 z4 = {0.f, 0.f, 0.f, 0.f};
    const int jlbase = wjj * 64 + l15;   // low-7 jloc base for this lane

    float best[8], second[8];
    int bchunk[8];
#pragma unroll
    for (int i = 0; i < 8; ++i) { best[i] = 3.4e38f; second[i] = 3.4e38f; bchunk[i] = 0; }

    for (int jt = 0; jt < 32; ++jt) {
        const char* Bc = (jt & 1) ? Bs1 : Bs0;
        char* Bn = (jt & 1) ? Bs0 : Bs1;
        if (jt < 31) STAGE_B(Bn, jt + 1);

        f32x4 acc[2][4];
#pragma unroll
        for (int kk = 0; kk < 4; ++kk) {
            half8 bb[4];
#pragma unroll
            for (int jf = 0; jf < 4; ++jf) {
                int row = wjj * 64 + jf * 16 + l15;
                int byte = row * 256 + ((kk * 64 + l4 * 16) ^ ((row & 15) << 4));
                bb[jf] = *(const half8*)(Bc + byte);
            }
#pragma unroll
            for (int mf = 0; mf < 2; ++mf)
#pragma unroll
                for (int jf = 0; jf < 4; ++jf)
                    acc[mf][jf] = __builtin_amdgcn_mfma_f32_16x16x32_f16(
                        areg[mf][kk], bb[jf], (kk == 0) ? z4 : acc[mf][jf], 0, 0, 0);
        }

        // ---- epilogue: packed (score|jloc), per-row min-tree + (best, second, chunk) ----
        float en[4];
#pragma unroll
        for (int jf = 0; jf < 4; ++jf) en[jf] = enk[jt * 128 + wjj * 64 + jf * 16 + l15];
#pragma unroll
        for (int mf = 0; mf < 2; ++mf)
#pragma unroll
            for (int r = 0; r < 4; ++r) {
                int ti = mf * 4 + r;
                float p0 = __uint_as_float((__float_as_uint(fmaf(-2.f, acc[mf][0][r], en[0])) & 0xFFFFFF80u) | (jlbase));
                float p1 = __uint_as_float((__float_as_uint(fmaf(-2.f, acc[mf][1][r], en[1])) & 0xFFFFFF80u) | (jlbase + 16));
                float p2 = __uint_as_float((__float_as_uint(fmaf(-2.f, acc[mf][2][r], en[2])) & 0xFFFFFF80u) | (jlbase + 32));
                float p3 = __uint_as_float((__float_as_uint(fmaf(-2.f, acc[mf][3][r], en[3])) & 0xFFFFFF80u) | (jlbase + 48));
                float m = fminf(fminf(p0, p1), fminf(p2, p3));
                second[ti] = fminf(second[ti], fmaxf(m, best[ti]));
                bool lt = m < best[ti];
                bchunk[ti] = lt ? jt : bchunk[ti];
                best[ti] = fminf(best[ti], m);
            }
        __syncthreads();   // next tile's staged buffer ready
    }

    // ---- merge across the 16 j-lanes sharing each row (packed values distinct per lane) ----
#pragma unroll
    for (int off = 1; off < 16; off <<= 1) {
#pragma unroll
        for (int ti = 0; ti < 8; ++ti) {
            float ob = __shfl_xor(best[ti], off);
            float os = __shfl_xor(second[ti], off);
            int oc = __shfl_xor(bchunk[ti], off);
            float ns = fminf(fmaxf(best[ti], ob), fminf(second[ti], os));
            bool take = ob < best[ti];
            bchunk[ti] = take ? oc : bchunk[ti];
            best[ti] = fminf(best[ti], ob);
            second[ti] = ns;
        }
    }

    // ---- merge the two wjj waves per row via LDS ----
    __syncthreads();
    float* tb = (float*)smem;          // [128][2]
    float* ts = tb + 256;              // [128][2]
    int*   tc = (int*)(ts + 256);      // [128][2]
    if (l15 == 0) {
#pragma unroll
        for (int ti = 0; ti < 8; ++ti) {
            int mf = ti >> 2, r = ti & 3;
            int row = wm * 32 + mf * 16 + l4 * 4 + r;
            tb[row * 2 + wjj] = best[ti];
            ts[row * 2 + wjj] = second[ti];
            tc[row * 2 + wjj] = bchunk[ti];
        }
    }
    __syncthreads();
    if (t < 128) {
        float b0 = tb[t * 2], b1 = tb[t * 2 + 1];
        float s0 = ts[t * 2], s1 = ts[t * 2 + 1];
        int   c0 = tc[t * 2], c1 = tc[t * 2 + 1];
        bool take1 = b1 < b0;                    // packed values distinct (wjj bit)
        float nb = fminf(b0, b1);
        float ns = fminf(fmaxf(b0, b1), fminf(s0, s1));
        int   nc = take1 ? c1 : c0;
        unsigned int nbits = __float_as_uint(nb);
        int nj = nc * 128 + (int)(nbits & 127u);
        int gidx = k * NPK + n0 + t;
        idxw[gidx] = nj;
        bestv[gidx] = __uint_as_float(nbits & 0xFFFFFF80u) - 512.f;
        if (ns - nb < MARGIN) {
            int p = atomicAdd(&cnt[k], 1);
            list[k * NPK + p] = gidx;
        }
    }
}

// ---------------- exact fp32 rescore: (4-row chunk) x (256-j slab) items ----------------
__global__ void k_rescore(const float* __restrict__ x, const float* __restrict__ embed,
                          const float* __restrict__ enorm, const int* __restrict__ list,
                          const int* __restrict__ cnt, u64* __restrict__ slots)
{
    __shared__ float xr[4][128];
    __shared__ u64 part[4][4];
    const int t = threadIdx.x;
    const int lane = t & 63, wv = t >> 6;
    const int c0 = cnt[0], c1 = cnt[1];
    const int items0 = ((c0 + 3) >> 2) * 16;
    const int items1 = ((c1 + 3) >> 2) * 16;
    const int total = items0 + items1;

    for (int item = blockIdx.x; item < total; item += gridDim.x) {
        int k, c, sl, ck;
        if (item < items0) { k = 0; c = item >> 4; sl = item & 15; ck = c0; }
        else { int it = item - items0; k = 1; c = it >> 4; sl = it & 15; ck = c1; }
        const int base = c * 4;
        const int cn = min(4, ck - base);
        __syncthreads();   // xr/part reuse safety
        for (int ii = t; ii < cn * 128; ii += 256) {
            int ri = ii >> 7, d = ii & 127;
            int gidx = list[k * NPK + base + ri];
            int n = gidx & (NPK - 1);
            int bb = n >> 10, hw = n & 1023;
            xr[ri][d] = x[((size_t)(bb * CCH + k * DIM + d)) * HW + hw];
        }
        __syncthreads();

        const int j = sl * 256 + t;
        float dot[4];
#pragma unroll
        for (int ri = 0; ri < 4; ++ri) dot[ri] = 0.f;
        const float* ek = embed + (size_t)k * DIM * NEMB + j;
        for (int d = 0; d < DIM; ++d) {
            float ev = ek[(size_t)d * NEMB];
#pragma unroll
            for (int ri = 0; ri < 4; ++ri) dot[ri] = fmaf(xr[ri][d], ev, dot[ri]);
        }
        const float en = enorm[k * NEMB + j];
        u64 key[4];
#pragma unroll
        for (int ri = 0; ri < 4; ++ri) {
            float sc = fmaf(-2.f, dot[ri], en);
            unsigned int bits = __float_as_uint(sc);
            unsigned int u = (sc >= 0.f) ? (bits | 0x80000000u) : ~bits;
            key[ri] = ((u64)u << 32) | (unsigned int)j;
        }
#pragma unroll
        for (int off = 32; off; off >>= 1) {
#pragma unroll
            for (int ri = 0; ri < 4; ++ri) {
                u64 o = __shfl_xor(key[ri], off);
                key[ri] = o < key[ri] ? o : key[ri];
            }
        }
        if (lane == 0) {
#pragma unroll
            for (int ri = 0; ri < 4; ++ri) part[wv][ri] = key[ri];
        }
        __syncthreads();
        if (t < 16) {
            int ri = t >> 2, w2 = t & 3;
            u64 kk = part[w2][ri];
            u64 o = __shfl_xor(kk, 1); kk = o < kk ? o : kk;
            o = __shfl_xor(kk, 2);     kk = o < kk ? o : kk;
            if (w2 == 0 && ri < cn)
                atomicMin(&slots[k * NPK + base + ri], kk);
        }
    }
}

// ---------------- write rescored winners + exact scores back ----------------
__global__ void k_fixup(const int* __restrict__ list, const int* __restrict__ cnt,
                        const u64* __restrict__ slots, int* __restrict__ idxw,
                        float* __restrict__ bestv) {
    int g = blockIdx.x * 256 + threadIdx.x;
#pragma unroll
    for (int k = 0; k < K_CB; ++k)
        if (g < cnt[k]) {
            u64 sl = slots[k * NPK + g];
            int gidx = list[k * NPK + g];
            idxw[gidx] = (int)(sl & 0xFFFFFFFFu);
            unsigned int u = (unsigned int)(sl >> 32);
            unsigned int bits = (u & 0x80000000u) ? (u & 0x7FFFFFFFu) : ~u;
            bestv[gidx] = __uint_as_float(bits);
        }
}

// ---------------- gather z_q + argf/hist (emit fused) ----------------
__global__ void k_gather(const float* __restrict__ embed, const int* __restrict__ idx,
                         float* __restrict__ zq, float* __restrict__ argf,
                         int* __restrict__ hist)
{
    const int blk = blockIdx.x;           // k*4096 + b*128 + d
    const int k = blk >> 12;
    const int b = (blk >> 7) & 31;
    const int d = blk & 127;
    const float* erow = embed + ((size_t)k * DIM + d) * NEMB;
    const int* idxr = idx + k * NPK + b * HW;
    float* zr = zq + ((size_t)b * CCH + (size_t)k * DIM + d) * HW;
    const int t = threadIdx.x;
#pragma unroll
    for (int i = 0; i < 4; ++i) {
        int h = i * 256 + t;
        int j = idxr[h];
        zr[h] = erow[j];
        if (d == 0) {
            argf[k * NPK + b * HW + h] = (float)j;
            atomicAdd(&hist[k * NEMB + j], 1);
        }
    }
}

// ---------------- diff partial sums: 64 blocks over the flat 65536 rows ----------------
__global__ void k_dsum(const float* __restrict__ rnorm, const float* __restrict__ bestv,
                       float* __restrict__ dpart)
{
    __shared__ float red[256];
    const int t = threadIdx.x;
    const int base = blockIdx.x * 1024;
    float s = 0.f;
#pragma unroll
    for (int i = 0; i < 4; ++i) {
        int g = base + i * 256 + t;
        s += rnorm[g] + bestv[g];
    }
    red[t] = s;
    __syncthreads();
    for (int off = 128; off > 0; off >>= 1) {
        if (t < off) red[t] += red[t + off];
        __syncthreads();
    }
    if (t == 0) dpart[blockIdx.x] = red[0];
}

// ---------------- finalize diffs + perplexity ----------------
__global__ void k_ppl(const float* __restrict__ dpart, const int* __restrict__ hist,
                      float* __restrict__ diffs, float* __restrict__ ppls)
{
    const int k = blockIdx.x;
    const int t = threadIdx.x;
    __shared__ float red[256];
    red[t] = (t < 32) ? dpart[k * 32 + t] : 0.f;
    __syncthreads();
    for (int off = 128; off > 0; off >>= 1) {
        if (t < off) red[t] += red[t + off];
        __syncthreads();
    }
    if (t == 0) diffs[k] = red[0] / (float)((size_t)NPK * DIM);
    __syncthreads();
    float s2 = 0.f;
    for (int i = t; i < NEMB; i += 256) {
        float p = (float)hist[k * NEMB + i] * (1.0f / (float)NPK);
        s2 += p * logf(p + 1e-10f);
    }
    red[t] = s2;
    __syncthreads();
    for (int off = 128; off > 0; off >>= 1) {
        if (t < off) red[t] += red[t + off];
        __syncthreads();
    }
    if (t == 0) ppls[k] = expf(-red[0]);
}

extern "C" void kernel_launch(void* const* d_in, const int* in_sizes, int n_in,
                              void* d_out, int out_size, void* d_ws, size_t ws_size,
                              hipStream_t stream) {
    const float* x = (const float*)d_in[0];       // [32,256,32,32]
    const float* embed = (const float*)d_in[1];   // [2,128,4096]
    float* out = (float*)d_out;
    float* zq    = out;                 // 8388608
    float* diffs = out + 8388608;       // 2
    float* argf  = out + 8388610;       // 65536 ([K,B,H,W] as float)
    float* ppls  = out + 8454146;       // 2

    char* W = (char*)d_ws;
    ushort* ebf   = (ushort*)W;                    // 2,097,152 : embedT fp16 [2][4096][128]
    float* enorm  = (float*)(W + 2097152);         // 32768 (exact, rescore)
    float* en512  = (float*)(W + 2129920);         // 32768 (+512, coarse)
    int*   idx    = (int*)(W + 2162688);           // 262144
    int*   hist   = (int*)(W + 2424832);           // 32768
    float* rnorm  = (float*)(W + 2457600);         // 262144
    float* bestv  = (float*)(W + 2719744);         // 262144
    int*   list   = (int*)(W + 2981888);           // 262144
    int*   cnt    = (int*)(W + 3244032);           // 64
    u64*   slots  = (u64*)(W + 3244096);           // 524288
    float* dpart  = (float*)(W + 3768384);         // 256 -> ends ~3.77 MB

    k_prep   <<<64,   256, 0, stream>>>(embed, ebf, enorm, en512, hist, cnt, slots);
    k_score  <<<512,  512, 0, stream>>>(x, ebf, en512, idx, bestv, rnorm, list, cnt);
    k_rescore<<<4096, 256, 0, stream>>>(x, embed, enorm, list, cnt, slots);
    k_fixup  <<<128,  256, 0, stream>>>(list, cnt, slots, idx, bestv);
    k_gather <<<8192, 256, 0, stream>>>(embed, idx, zq, argf, hist);
    k_dsum   <<<64,   256, 0, stream>>>(rnorm, bestv, dpart);
    k_ppl    <<<2,    256, 0, stream>>>(dpart, hist, diffs, ppls);
}